// Round 13
// baseline (183.655 us; speedup 1.0000x reference)
//
#include <hip/hip_runtime.h>

// (B,H,S,D) = (2,16,2048,64), fp32 in/out, causal. Flash-attention fwd.
// Round 11 (3rd resubmit; rounds 10-12 benches were GPUAcquisitionTimeouts,
// kernel never ran). Max-TLP redesign. Evidence R7/R9/R10: dur tracks
// waves/SIMD (57us @ ~6, 92 @ ~4, 91 @ ~2); prefetch/dbuf/barrier-count all
// neutral. Latency-bound + TLP-starved. Doubles residency to 8 waves/SIMD:
//   - 512-thr blocks (8 waves = 2 strips x 4 key-quarters), grid 1024
//     -> 4 blocks/CU x 8 waves = 32 waves/CU (static max).
//   - total regs <= 64/wave (unified VGPR+AGPR pool): Q moved to LDS
//     (qf read per-MFMA like kf), NO prefetch regs; acc oT=32 in AGPR,
//     arch ~32. Enforced with __launch_bounds__(512, 8).
//   - LDS 40KB: Qs 8K | KB[4kq] 16K | VT[4kq] 16K; single-buffered,
//     2 BAR_LGKM/iter (R5's proven protocol); kq-pair (2 strips) shares
//     staging via R5's 128-thread roles. Latency hidden by 4 blocks/CU.
//   - split-K-4 additive partials (fixed-shift exp2), LDS combine per strip.
#define SEQ 2048
#define HD  64
#define SCALE 0.18033688011111772f   // 0.125 * log2(e)

typedef __bf16 bf16x8 __attribute__((ext_vector_type(8)));
typedef __bf16 bf16x2 __attribute__((ext_vector_type(2)));
typedef float  f32x4  __attribute__((ext_vector_type(4)));
typedef float  f32x16 __attribute__((ext_vector_type(16)));

// Workgroup barrier WITHOUT the vmcnt(0) drain __syncthreads() emits.
#define BAR_LGKM() asm volatile("s_waitcnt lgkmcnt(0)\n\ts_barrier" ::: "memory")

union PU { unsigned u[4]; bf16x8 v; };

__device__ __forceinline__ unsigned pk2(float lo, float hi) {
    union { unsigned u; bf16x2 v; } t;
    t.v = bf16x2{(__bf16)lo, (__bf16)hi};
    return t.u;
}

// Swap high half of x (lanes 32-63) with low half of y (lanes 0-31).
__device__ __forceinline__ void plswap(unsigned &x, unsigned &y) {
#if __has_builtin(__builtin_amdgcn_permlane32_swap)
    auto r = __builtin_amdgcn_permlane32_swap(x, y, false, false);
    x = (unsigned)r[0];
    y = (unsigned)r[1];
#else
    asm("v_permlane32_swap_b32 %0, %1" : "+v"(x), "+v"(y));
#endif
}

__global__ __launch_bounds__(512, 8) void attn_fwd(
    const float* __restrict__ Q,
    const float* __restrict__ K,
    const float* __restrict__ V,
    float* __restrict__ O)
{
    // smem: Qs[64 row][64 d] bf16 (8KB, XOR-swizzled)
    //       KB[kq][32 key][64 d] bf16 (4KB each) | VT[kq][64 d][32 key] (4KB).
    // Combine scratch (post-loop, barrier-guarded): 3 x 2112 f32 = 25344B.
    __shared__ __align__(16) unsigned char smem[40960];
    #define QSp(r,c8)      ((__bf16*)(smem +          (((r)<<7)  + ((c8)<<4))))
    #define KBq(kq,key,c8) ((__bf16*)(smem +  8192 + ((kq)<<12) + (((key)<<7) + ((c8)<<4))))
    #define VTq(kq,r,c8)   ((__bf16*)(smem + 24576 + ((kq)<<12) + (((r)<<6)   + ((c8)<<4))))
    #define OSc(w)         ((float*)(smem + (w)*8448))   // w in {0,1,2}

    const int tid  = threadIdx.x;
    const int w    = tid >> 6;
    const int lane = tid & 63;
    const int n    = lane & 31;     // MFMA m/n lane index
    const int p    = lane >> 5;     // k-half-of-16 selector
    const int kq   = w & 3;         // key-quarter (round-robin mod 4)
    const int st   = w >> 2;        // strip 0/1 within the 64-row q-tile

    // Block -> (bh, q-tile). Same-bh blocks map to one XCD (x%8 fixed).
    // Co-resident q-values {s, s+8, 31-s, 23-s} sum to 62 (CU balance).
    const int x  = blockIdx.x;
    const int bh = x & 31;
    const int sr = x >> 5;
    const int s  = (sr & 16) ? (31 - (sr & 15)) : sr;

    const int R0   = s * 64 + st * 32;       // wave's first query row
    const int imax = (2 * s + 5) >> 2;       // uniform loop count (ceil((2s+2)/4))

    const float* __restrict__ Qh = Q + (size_t)bh * SEQ * HD;
    const float* __restrict__ Kh = K + (size_t)bh * SEQ * HD;
    const float* __restrict__ Vh = V + (size_t)bh * SEQ * HD;
    float* __restrict__       Oh = O + (size_t)bh * SEQ * HD;

    // ---- Q prologue: 512 threads stage 64 rows x 64 d (scale pre-folded) ----
    {
        const int r = tid >> 3;              // q-row 0..63
        const int c = tid & 7;               // 8-float d chunk
        const float* qp = Qh + (size_t)(s * 64 + r) * HD + c * 8;
        f32x4 a = *(const f32x4*)(qp);
        f32x4 b = *(const f32x4*)(qp + 4);
        bf16x8 wq;
        #pragma unroll
        for (int j = 0; j < 4; ++j) {
            wq[j]     = (__bf16)(a[j] * SCALE);
            wq[4 + j] = (__bf16)(b[j] * SCALE);
        }
        *(bf16x8*)QSp(r, c ^ (r & 7)) = wq;
    }

    f32x16 oT[2] = {};      // O^T partial accumulators (d-halves)
    float  l_own = 0.f;     // partial row-sum (this lane's key slots)

    // ---- staging roles: kq-pair = 128 threads (local = st*64+lane) ----
    const int local = (st << 6) | lane;
    const int key_s = local >> 2;        // K: key row 0..31
    const int dgi   = local & 3;         // K: 16-float d group
    const int swk   = key_s & 7;
    const int Ls    = local & 31;        // V: d-pair (2Ls, 2Ls+1)
    const int ko    = local >> 5;        // V: 8-key group 0..3
    const int swv   = Ls & 3;

    const float* kroot = Kh + (size_t)key_s * HD + dgi * 16;
    const float* vroot = Vh + (size_t)(ko * 8) * HD + 2 * Ls;

    #pragma unroll 1
    for (int i = 0; i < imax; ++i) {
        const int T = 4 * i + kq;

        BAR_LGKM();   // prior tile's fragment reads complete (Q staged, i=0)

        if (T <= 2 * s + 1) {   // stage for the longer (strip-1) span
            // K rows (sequential with V to cap live regs)
            {
                const float* kp = kroot + (size_t)(32 * T) * HD;
                f32x4 k0 = *(const f32x4*)(kp);
                f32x4 k1 = *(const f32x4*)(kp + 4);
                f32x4 k2 = *(const f32x4*)(kp + 8);
                f32x4 k3 = *(const f32x4*)(kp + 12);
                bf16x8 w0, w1;
                #pragma unroll
                for (int j = 0; j < 4; ++j) {
                    w0[j] = (__bf16)k0[j]; w0[4 + j] = (__bf16)k1[j];
                    w1[j] = (__bf16)k2[j]; w1[4 + j] = (__bf16)k3[j];
                }
                *(bf16x8*)KBq(kq, key_s, (2 * dgi)     ^ swk) = w0;
                *(bf16x8*)KBq(kq, key_s, (2 * dgi + 1) ^ swk) = w1;
            }
            // V columns (transposed)
            {
                const float* vp = vroot + (size_t)(32 * T) * HD;
                float2 vv[8];
                #pragma unroll
                for (int j = 0; j < 8; ++j) vv[j] = *(const float2*)(vp + (size_t)j * HD);
                bf16x8 v0, v1;
                #pragma unroll
                for (int j = 0; j < 8; ++j) { v0[j] = (__bf16)vv[j].x; v1[j] = (__bf16)vv[j].y; }
                *(bf16x8*)VTq(kq, 2 * Ls,     ko ^ swv) = v0;
                *(bf16x8*)VTq(kq, 2 * Ls + 1, ko ^ swv) = v1;
            }
        }

        BAR_LGKM();   // staged tile visible

        if (T <= 2 * s + st) {
            __builtin_amdgcn_s_setprio(1);
            // ---- S^T = K Q^T : qf and kf both from LDS ----
            f32x16 sT = {};
            #pragma unroll
            for (int cc = 0; cc < 4; ++cc) {
                bf16x8 kf = *(const bf16x8*)KBq(kq, n, (2 * cc + p) ^ (n & 7));
                bf16x8 qf = *(const bf16x8*)QSp(st * 32 + n, (2 * cc + p) ^ (n & 7));
                sT = __builtin_amdgcn_mfma_f32_32x32x16_bf16(kf, qf, sT, 0, 0, 0);
            }

            const bool diag = (T == 2 * s + st);
            float ts = 0.f;
            #pragma unroll
            for (int r = 0; r < 16; ++r) {
                float pe = __builtin_amdgcn_exp2f(sT[r]);   // scale folded into Q
                if (diag) {
                    const int kk = (r & 3) + 8 * (r >> 2) + 4 * p;
                    pe = (kk <= n) ? pe : 0.f;
                }
                sT[r] = pe;           // in-place: pv = sT (register reuse)
                ts += pe;
            }
            l_own += ts;

            // ---- P: C-layout -> B-layout in-register (pack + permlane32_swap) ----
            unsigned a0 = pk2(sT[0],  sT[1]),  a1 = pk2(sT[2],  sT[3]);
            unsigned a2 = pk2(sT[4],  sT[5]),  a3 = pk2(sT[6],  sT[7]);
            unsigned b0 = pk2(sT[8],  sT[9]),  b1 = pk2(sT[10], sT[11]);
            unsigned b2 = pk2(sT[12], sT[13]), b3 = pk2(sT[14], sT[15]);
            plswap(a0, a2);
            plswap(a1, a3);
            plswap(b0, b2);
            plswap(b1, b3);
            PU pu0, pu1;
            pu0.u[0] = a0; pu0.u[1] = a1; pu0.u[2] = a2; pu0.u[3] = a3;
            pu1.u[0] = b0; pu1.u[1] = b1; pu1.u[2] = b2; pu1.u[3] = b3;
            bf16x8 pf0 = pu0.v;
            bf16x8 pf1 = pu1.v;

            // ---- O^T += V^T P^T ----
            const int swn = (n >> 1) & 3;
            #pragma unroll
            for (int dg = 0; dg < 2; ++dg) {
                bf16x8 vf0 = *(const bf16x8*)VTq(kq, 32 * dg + n, p ^ swn);
                bf16x8 vf1 = *(const bf16x8*)VTq(kq, 32 * dg + n, (2 + p) ^ swn);
                oT[dg] = __builtin_amdgcn_mfma_f32_32x32x16_bf16(vf0, pf0, oT[dg], 0, 0, 0);
                oT[dg] = __builtin_amdgcn_mfma_f32_32x32x16_bf16(vf1, pf1, oT[dg], 0, 0, 0);
            }
            __builtin_amdgcn_s_setprio(0);
        }
    }

    // ---- combine 4 key-quarter partials per strip (additive: fixed-shift) ----
    float l_part = l_own + __shfl_xor(l_own, 32, 64);

    #pragma unroll 1
    for (int st2 = 0; st2 < 2; ++st2) {
        __syncthreads();                 // staging dead / scratch free
        if (st == st2 && kq != 0) {
            #pragma unroll
            for (int dg = 0; dg < 2; ++dg)
                #pragma unroll
                for (int r = 0; r < 16; ++r)
                    OSc(kq - 1)[(dg * 16 + r) * 64 + lane] = oT[dg][r];
            OSc(kq - 1)[2048 + lane] = l_part;
        }
        __syncthreads();                 // partials visible
        if (st == st2 && kq == 0) {
            const float lsum = l_part + OSc(0)[2048 + lane]
                                      + OSc(1)[2048 + lane]
                                      + OSc(2)[2048 + lane];
            const float linv = 1.0f / lsum;
            #pragma unroll
            for (int dg = 0; dg < 2; ++dg) {
                #pragma unroll
                for (int u4 = 0; u4 < 4; ++u4) {
                    f32x4 o;
                    #pragma unroll
                    for (int j = 0; j < 4; ++j) {
                        const int r   = 4 * u4 + j;
                        const int idx = (dg * 16 + r) * 64 + lane;
                        o[j] = (oT[dg][r] + OSc(0)[idx] + OSc(1)[idx] + OSc(2)[idx]) * linv;
                    }
                    *(f32x4*)&Oh[(size_t)(R0 + n) * HD + dg * 32 + u4 * 8 + 4 * p] = o;
                }
            }
        }
    }
}

extern "C" void kernel_launch(void* const* d_in, const int* in_sizes, int n_in,
                              void* d_out, int out_size, void* d_ws, size_t ws_size,
                              hipStream_t stream) {
    const float* Q = (const float*)d_in[0];
    const float* K = (const float*)d_in[1];
    const float* V = (const float*)d_in[2];
    // d_in[3]: causal mask — analytically tril, not read.
    float* O = (float*)d_out;

    dim3 grid(1024);
    dim3 block(512);
    attn_fwd<<<grid, block, 0, stream>>>(Q, K, V, O);
}

// Round 15
// 135.165 us; speedup vs baseline: 1.3587x; 1.3587x over previous
//
#include <hip/hip_runtime.h>

// (B,H,S,D) = (2,16,2048,64), fp32 in/out, causal. Flash-attention fwd.
// Round 14 (resubmit; prior bench was GPUAcquisitionTimeout, never ran).
// BK=64 on the champion R7 structure. Model from R7/R9/R10/R11:
// makespan = longest-block iters x T_chain (~4300cy); occupancy is a
// consequence (drain), not a cause (24/39/19/58% occ gave 57/92/91/102us).
// R11's regression was pure spill traffic (+70MB/dispatch HBM). So: halve
// the iteration count instead of raising TLP.
//   - Each iteration stages+computes a PAIR of 32-key sub-tiles; the old
//     double-buffer index b becomes the sub-tile index (LDS layout and all
//     swizzles byte-identical to R7, 32KB).
//   - R5's proven 2-barrier protocol; prefetch of the next pair issued
//     between the barriers (vmcnt not drained by BAR_LGKM; covered by the
//     compute phase). Longest chain: 32 -> 16 iterations.
//   - Two independent sT chains per iteration -> intra-wave ILP fills
//     latencies the halved barrier count exposes.
//   - __launch_bounds__(256,3): ~170-reg cap fits the doubled prefetch
//     (kst[2][4]+vst[2][8] = 64 regs) with NO spills (R11 tripwire:
//     FETCH/WRITE must stay ~28/16MB).
// Unchanged: split-K-2 key-halves, transposed matmuls (S^T = K Q^T,
// O^T = V^T P^T), scale folded into Q, in-register P via permlane32_swap,
// fixed-shift additive partials, LDS combine epilogue, zigzag CU balance.
#define SEQ 2048
#define HD  64
#define SCALE 0.18033688011111772f   // 0.125 * log2(e)

typedef __bf16 bf16x8 __attribute__((ext_vector_type(8)));
typedef __bf16 bf16x2 __attribute__((ext_vector_type(2)));
typedef float  f32x4  __attribute__((ext_vector_type(4)));
typedef float  f32x16 __attribute__((ext_vector_type(16)));

// Workgroup barrier WITHOUT the vmcnt(0) drain __syncthreads() emits.
// LDS visibility across waves needs only lgkmcnt(0) + s_barrier on CDNA.
#define BAR_LGKM() asm volatile("s_waitcnt lgkmcnt(0)\n\ts_barrier" ::: "memory")

union PU { unsigned u[4]; bf16x8 v; };

__device__ __forceinline__ unsigned pk2(float lo, float hi) {
    union { unsigned u; bf16x2 v; } t;
    t.v = bf16x2{(__bf16)lo, (__bf16)hi};
    return t.u;
}

// Swap high half of x (lanes 32-63) with low half of y (lanes 0-31).
__device__ __forceinline__ void plswap(unsigned &x, unsigned &y) {
#if __has_builtin(__builtin_amdgcn_permlane32_swap)
    auto r = __builtin_amdgcn_permlane32_swap(x, y, false, false);
    x = (unsigned)r[0];
    y = (unsigned)r[1];
#else
    asm("v_permlane32_swap_b32 %0, %1" : "+v"(x), "+v"(y));
#endif
}

__global__ __launch_bounds__(256, 3) void attn_fwd(
    const float* __restrict__ Q,
    const float* __restrict__ K,
    const float* __restrict__ V,
    float* __restrict__ O)
{
    // smem carve (identical bytes to R7): Kb[2 kh][2 sub][32][64] bf16 (16KB) |
    //             Vt[2 kh][2 sub][64][32] bf16 (16KB).
    // Epilogue reuses [0, 16.9KB) as f32 (tile buffers dead by then).
    __shared__ __align__(16) unsigned char smem[32768];
    #define KBp(kh,b,key,c8) ((__bf16*)(smem +         (((kh)<<13) + ((b)<<12) + ((key)<<7) + ((c8)<<4))))
    #define VTp(kh,b,r,c8)   ((__bf16*)(smem + 16384 + (((kh)<<13) + ((b)<<12) + ((r)<<6)   + ((c8)<<4))))

    const int tid   = threadIdx.x;
    const int wave  = tid >> 6;
    const int lane  = tid & 63;
    const int n     = lane & 31;    // MFMA m/n lane index
    const int p     = lane >> 5;    // k-half-of-16 selector
    const int strip = wave & 1;     // which 32-row strip of the 64-row q-tile
    const int kh    = wave >> 1;    // key-half: 0 = low keys, 1 = high keys

    // Block -> (bh, q-tile). Same-bh blocks map to one XCD (x%8 fixed).
    // Co-resident q-values {s, s+8, 31-s, 23-s} sum to 62 (CU balance).
    const int x  = blockIdx.x;
    const int bh = x & 31;
    const int s  = x >> 5;
    const int q  = (s & 16) ? (31 - (s & 15)) : s;

    const int q0   = q * 64 + strip * 32;   // wave's first query row
    const int nt   = q + 1;                 // 32-key sub-tiles per key-half
    const int jmax = (nt + 1) >> 1;         // 64-key iterations
    const int tS0  = kh * nt;               // this half's first 32-key tile

    const float* __restrict__ Qh = Q + (size_t)bh * SEQ * HD;
    const float* __restrict__ Kh = K + (size_t)bh * SEQ * HD;
    const float* __restrict__ Vh = V + (size_t)bh * SEQ * HD;
    float* __restrict__       Oh = O + (size_t)bh * SEQ * HD;

    // ---- Q fragments (B-operand layout), scale pre-folded ----
    bf16x8 qf[4];
    {
        const float* qrow = Qh + (size_t)(q0 + n) * HD;
        #pragma unroll
        for (int c = 0; c < 4; ++c) {
            f32x4 a = *(const f32x4*)(qrow + 16 * c + 8 * p);
            f32x4 b = *(const f32x4*)(qrow + 16 * c + 8 * p + 4);
            #pragma unroll
            for (int j = 0; j < 4; ++j) {
                qf[c][j]     = (__bf16)(a[j] * SCALE);
                qf[c][4 + j] = (__bf16)(b[j] * SCALE);
            }
        }
    }

    f32x16 oT[2] = {};      // O^T accumulators (d-halves)
    float  l_own = 0.f;     // partial row-sum (this lane's 16-key columns)

    // ---- staging assignment: 128 threads per key-half buffer ----
    const int local = tid & 127;
    const int key_s = local >> 2;        // K: key row 0..31
    const int dgi   = local & 3;         // K: 16-float d group
    const int Ls    = local & 31;        // V: d-pair (2Ls, 2Ls+1)
    const int ko    = local >> 5;        // V: 8-key group 0..3
    const int swk   = key_s & 7;
    const int swv   = Ls & 3;

    const float* kbase = Kh + (size_t)key_s * HD + dgi * 16;
    const float* vbase = Vh + (size_t)(ko * 8) * HD + 2 * Ls;

    f32x4  kst[2][4];    // prefetched pair (2 sub-tiles x 4 f32x4)
    float2 vst[2][8];    // prefetched pair (2 sub-tiles x 8 float2)

    auto loadt = [&](int j) {   // global -> regs (sub-tiles 2j, 2j+1)
        #pragma unroll
        for (int t = 0; t < 2; ++t) {
            const int s32 = 2 * j + t;
            if (s32 < nt) {
                const size_t off = (size_t)(32 * (tS0 + s32)) * HD;
                const float* kp = kbase + off;
                #pragma unroll
                for (int jj = 0; jj < 4; ++jj) kst[t][jj] = *(const f32x4*)(kp + 4 * jj);
                const float* vp = vbase + off;
                #pragma unroll
                for (int jj = 0; jj < 8; ++jj) vst[t][jj] = *(const float2*)(vp + (size_t)jj * HD);
            }
        }
    };

    auto stage = [&](int j) {   // regs -> LDS (cvt bf16; V transposed; swizzled)
        #pragma unroll
        for (int t = 0; t < 2; ++t) {
            const int s32 = 2 * j + t;
            if (s32 < nt) {
                bf16x8 w0, w1;
                #pragma unroll
                for (int jj = 0; jj < 4; ++jj) {
                    w0[jj] = (__bf16)kst[t][0][jj]; w0[4 + jj] = (__bf16)kst[t][1][jj];
                    w1[jj] = (__bf16)kst[t][2][jj]; w1[4 + jj] = (__bf16)kst[t][3][jj];
                }
                *(bf16x8*)KBp(kh, t, key_s, (2 * dgi)     ^ swk) = w0;
                *(bf16x8*)KBp(kh, t, key_s, (2 * dgi + 1) ^ swk) = w1;

                bf16x8 v0, v1;
                #pragma unroll
                for (int jj = 0; jj < 8; ++jj) { v0[jj] = (__bf16)vst[t][jj].x; v1[jj] = (__bf16)vst[t][jj].y; }
                *(bf16x8*)VTp(kh, t, 2 * Ls,     ko ^ swv) = v0;
                *(bf16x8*)VTp(kh, t, 2 * Ls + 1, ko ^ swv) = v1;
            }
        }
    };

    loadt(0);   // prologue: first pair in flight

    #pragma unroll 1
    for (int j = 0; j < jmax; ++j) {
        BAR_LGKM();   // prior iteration's fragment reads complete

        stage(j);                       // vmcnt wait covered by prior compute
        if (j + 1 < jmax) loadt(j + 1); // issue next pair; stays in flight

        BAR_LGKM();   // staged pair visible

        __builtin_amdgcn_s_setprio(1);
        #pragma unroll
        for (int b = 0; b < 2; ++b) {
            const int i = 2 * j + b;    // sub-tile index within key-half
            // key-half B, strip 0 skips its all-masked last tile
            if (i < nt && (!kh || (i < q + strip))) {
                // ---- S^T = K Q^T : one 32x32 frag over 4 d-chunks ----
                f32x16 sT = {};
                #pragma unroll
                for (int cc = 0; cc < 4; ++cc) {
                    bf16x8 kf = *(const bf16x8*)KBp(kh, b, n, (2 * cc + p) ^ (n & 7));
                    sT = __builtin_amdgcn_mfma_f32_32x32x16_bf16(kf, qf[cc], sT, 0, 0, 0);
                }

                const bool diag = (tS0 + i == 2 * q + strip);
                float ts = 0.f;
                #pragma unroll
                for (int r = 0; r < 16; ++r) {
                    float pe = __builtin_amdgcn_exp2f(sT[r]);   // scale folded into Q
                    if (diag) {
                        const int kk = (r & 3) + 8 * (r >> 2) + 4 * p;
                        pe = (kk <= n) ? pe : 0.f;
                    }
                    sT[r] = pe;
                    ts += pe;
                }
                l_own += ts;

                // ---- P: C-layout -> B-layout in-register ----
                unsigned a0 = pk2(sT[0],  sT[1]),  a1 = pk2(sT[2],  sT[3]);
                unsigned a2 = pk2(sT[4],  sT[5]),  a3 = pk2(sT[6],  sT[7]);
                unsigned b0 = pk2(sT[8],  sT[9]),  b1 = pk2(sT[10], sT[11]);
                unsigned b2 = pk2(sT[12], sT[13]), b3 = pk2(sT[14], sT[15]);
                plswap(a0, a2);
                plswap(a1, a3);
                plswap(b0, b2);
                plswap(b1, b3);
                PU pu0, pu1;
                pu0.u[0] = a0; pu0.u[1] = a1; pu0.u[2] = a2; pu0.u[3] = a3;
                pu1.u[0] = b0; pu1.u[1] = b1; pu1.u[2] = b2; pu1.u[3] = b3;
                bf16x8 pf0 = pu0.v;
                bf16x8 pf1 = pu1.v;

                // ---- O^T += V^T P^T ----
                const int swn = (n >> 1) & 3;
                #pragma unroll
                for (int dg = 0; dg < 2; ++dg) {
                    bf16x8 vf0 = *(const bf16x8*)VTp(kh, b, 32 * dg + n, p ^ swn);
                    bf16x8 vf1 = *(const bf16x8*)VTp(kh, b, 32 * dg + n, (2 + p) ^ swn);
                    oT[dg] = __builtin_amdgcn_mfma_f32_32x32x16_bf16(vf0, pf0, oT[dg], 0, 0, 0);
                    oT[dg] = __builtin_amdgcn_mfma_f32_32x32x16_bf16(vf1, pf1, oT[dg], 0, 0, 0);
                }
            }
        }
        __builtin_amdgcn_s_setprio(0);
    }

    // ---- combine key-halves (partials are additive: fixed-shift softmax) ----
    __syncthreads();                        // tile buffers dead; reuse as f32
    float* Os = (float*)smem;
    const int cb = strip * 2112;            // 2048 O-partials + 64 l-partials
    float l_part = l_own + __shfl_xor(l_own, 32, 64);

    if (kh == 1) {
        #pragma unroll
        for (int dg = 0; dg < 2; ++dg)
            #pragma unroll
            for (int r = 0; r < 16; ++r)
                Os[cb + (dg * 16 + r) * 64 + lane] = oT[dg][r];
        Os[cb + 2048 + lane] = l_part;
    }
    __syncthreads();
    if (kh == 0) {
        const float linv = 1.0f / (l_part + Os[cb + 2048 + lane]);
        #pragma unroll
        for (int dg = 0; dg < 2; ++dg) {
            #pragma unroll
            for (int u = 0; u < 4; ++u) {
                f32x4 o;
                #pragma unroll
                for (int j = 0; j < 4; ++j) {
                    const int r = 4 * u + j;
                    o[j] = (oT[dg][r] + Os[cb + (dg * 16 + r) * 64 + lane]) * linv;
                }
                *(f32x4*)&Oh[(size_t)(q0 + n) * HD + dg * 32 + u * 8 + 4 * p] = o;
            }
        }
    }
}

extern "C" void kernel_launch(void* const* d_in, const int* in_sizes, int n_in,
                              void* d_out, int out_size, void* d_ws, size_t ws_size,
                              hipStream_t stream) {
    const float* Q = (const float*)d_in[0];
    const float* K = (const float*)d_in[1];
    const float* V = (const float*)d_in[2];
    // d_in[3]: causal mask — analytically tril, not read.
    float* O = (float*)d_out;

    dim3 grid(1024);
    dim3 block(256);
    attn_fwd<<<grid, block, 0, stream>>>(Q, K, V, O);
}

// Round 21
// 125.437 us; speedup vs baseline: 1.4641x; 1.0776x over previous
//
#include <hip/hip_runtime.h>

// (B,H,S,D) = (2,16,2048,64), fp32 in/out, causal. Flash-attention fwd.
// Round 16 (5th resubmit; rounds 16-20 benches were GPUAcquisitionTimeouts,
// kernel never ran). QBLK=128 — halve logical K/V cache traffic. Unified
// model from R5-R14: time ~ staged K/V volume / ~9-11.5 TB/s L2/L3
// throughput (R7/R14: 528MB -> 57-63us; R9/R10: 1056MB -> 91us; barriers/
// prefetch/TLP/BK all neutral at fixed traffic). Doubling Q-rows per staged
// tile halves the volume: 272MB.
//   - 512-thr block, 8 waves = 4 strips x 2 key-halves over 128 q-rows.
//   - Staging: 256 threads per key-half tile (6 loads/thread), same LDS
//     layout/swizzles as R7 (byte-identical final layout), R7's proven
//     1-barrier double-buffer protocol.
//   - split-K-2 combine per strip (R7 epilogue x4 strips, 33792B scratch).
//   - zigzag pairing: CU gets s and 15-s -> uniform 34 iters/CU, 2 blk/CU.
// Longest block stays 32 iters (R7 scale): serial-model worst case is
// neutral, traffic-model prediction is 32-40us/dispatch.
#define SEQ 2048
#define HD  64
#define SCALE 0.18033688011111772f   // 0.125 * log2(e)

typedef __bf16 bf16x8 __attribute__((ext_vector_type(8)));
typedef __bf16 bf16x4 __attribute__((ext_vector_type(4)));
typedef __bf16 bf16x2 __attribute__((ext_vector_type(2)));
typedef float  f32x4  __attribute__((ext_vector_type(4)));
typedef float  f32x16 __attribute__((ext_vector_type(16)));

// Workgroup barrier WITHOUT the vmcnt(0) drain __syncthreads() emits.
// LDS visibility across waves needs only lgkmcnt(0) + s_barrier on CDNA.
#define BAR_LGKM() asm volatile("s_waitcnt lgkmcnt(0)\n\ts_barrier" ::: "memory")

union PU { unsigned u[4]; bf16x8 v; };

__device__ __forceinline__ unsigned pk2(float lo, float hi) {
    union { unsigned u; bf16x2 v; } t;
    t.v = bf16x2{(__bf16)lo, (__bf16)hi};
    return t.u;
}

// Swap high half of x (lanes 32-63) with low half of y (lanes 0-31).
__device__ __forceinline__ void plswap(unsigned &x, unsigned &y) {
#if __has_builtin(__builtin_amdgcn_permlane32_swap)
    auto r = __builtin_amdgcn_permlane32_swap(x, y, false, false);
    x = (unsigned)r[0];
    y = (unsigned)r[1];
#else
    asm("v_permlane32_swap_b32 %0, %1" : "+v"(x), "+v"(y));
#endif
}

__global__ __launch_bounds__(512, 2) void attn_fwd(
    const float* __restrict__ Q,
    const float* __restrict__ K,
    const float* __restrict__ V,
    float* __restrict__ O)
{
    // smem: Kb[2 kh][2 buf][32][64] bf16 (16KB) | Vt[2 kh][2 buf][64][32] (16KB).
    // Epilogue reuses [0, 33792) as f32 combine scratch (4 strips x 2112).
    __shared__ __align__(16) unsigned char smem[33792];
    #define KBp(kh,b,key,c8) ((__bf16*)(smem +         (((kh)<<13) + ((b)<<12) + ((key)<<7) + ((c8)<<4))))
    #define VTp(kh,b,r,c8)   ((__bf16*)(smem + 16384 + (((kh)<<13) + ((b)<<12) + ((r)<<6)   + ((c8)<<4))))

    const int tid  = threadIdx.x;
    const int wave = tid >> 6;      // 0..7
    const int lane = tid & 63;
    const int n    = lane & 31;     // MFMA m/n lane index
    const int p    = lane >> 5;     // k-half-of-16 selector
    const int w3   = wave & 3;      // strip 0..3 within the 128-row q-tile
    const int kh   = wave >> 2;     // key-half: 0 = low keys, 1 = high keys

    // Block -> (bh, 128-row q-tile). Same-bh blocks on one XCD (x%8 fixed).
    // CU pairs blocks (sr, sr+8) -> s-pair (s, 15-s): uniform 34 iters/CU.
    const int x  = blockIdx.x;
    const int bh = x & 31;
    const int sr = x >> 5;                       // 0..15
    const int s  = (sr & 8) ? (15 - (sr & 7)) : sr;

    const int R0   = s * 128 + w3 * 32;          // wave's first query row
    const int span = 4 * s + w3;                 // strip's last (diagonal) tile
    const int jmax = 2 * s + 2;                  // iters per key-half (uniform)
    const int tB   = kh * jmax;                  // this half's first tile

    const float* __restrict__ Qh = Q + (size_t)bh * SEQ * HD;
    const float* __restrict__ Kh = K + (size_t)bh * SEQ * HD;
    const float* __restrict__ Vh = V + (size_t)bh * SEQ * HD;
    float* __restrict__       Oh = O + (size_t)bh * SEQ * HD;

    // ---- Q fragments (B-operand layout), scale pre-folded ----
    bf16x8 qf[4];
    {
        const float* qrow = Qh + (size_t)(R0 + n) * HD;
        #pragma unroll
        for (int c = 0; c < 4; ++c) {
            f32x4 a = *(const f32x4*)(qrow + 16 * c + 8 * p);
            f32x4 b = *(const f32x4*)(qrow + 16 * c + 8 * p + 4);
            #pragma unroll
            for (int j = 0; j < 4; ++j) {
                qf[c][j]     = (__bf16)(a[j] * SCALE);
                qf[c][4 + j] = (__bf16)(b[j] * SCALE);
            }
        }
    }

    f32x16 oT[2] = {};      // O^T accumulators (d-halves)
    float  l_own = 0.f;     // partial row-sum (this lane's 16-key columns)

    // ---- staging roles: 256 threads per key-half tile (sg = which half) ----
    const int sg    = tid >> 8;          // staged key-half
    const int t8    = tid & 255;
    const int key_s = t8 >> 3;           // K: key row 0..31
    const int dgi8  = t8 & 7;            // K: 8-float d group
    const int swk   = key_s & 7;
    const int Ls    = t8 & 31;           // V: d-pair (2Ls, 2Ls+1)
    const int ko    = t8 >> 5;           // V: 4-key group 0..7
    const int swv   = Ls & 3;
    const int ku    = ko >> 1;           // 16B chunk
    const int khalf = ko & 1;            // half-chunk (4 keys)

    const float* kbase = Kh + (size_t)key_s * HD + dgi8 * 8;
    const float* vbase = Vh + (size_t)(ko * 4) * HD + 2 * Ls;

    f32x4  kst[2];      // prefetched K slice
    float2 vst[4];      // prefetched V slice

    auto loadt = [&](int j) {   // global -> regs (this group's tile sg*jmax+j)
        const size_t off = (size_t)(32 * (sg * jmax + j)) * HD;
        const float* kp = kbase + off;
        kst[0] = *(const f32x4*)(kp);
        kst[1] = *(const f32x4*)(kp + 4);
        const float* vp = vbase + off;
        #pragma unroll
        for (int jj = 0; jj < 4; ++jj) vst[jj] = *(const float2*)(vp + (size_t)jj * HD);
    };

    auto stage = [&](int b) {   // regs -> LDS buf b (cvt bf16; V transposed; swizzled)
        bf16x8 w0;
        #pragma unroll
        for (int j = 0; j < 4; ++j) { w0[j] = (__bf16)kst[0][j]; w0[4 + j] = (__bf16)kst[1][j]; }
        *(bf16x8*)KBp(sg, b, key_s, dgi8 ^ swk) = w0;

        bf16x4 v0, v1;
        #pragma unroll
        for (int j = 0; j < 4; ++j) { v0[j] = (__bf16)vst[j].x; v1[j] = (__bf16)vst[j].y; }
        *(bf16x4*)(VTp(sg, b, 2 * Ls,     ku ^ swv) + 4 * khalf) = v0;
        *(bf16x4*)(VTp(sg, b, 2 * Ls + 1, ku ^ swv) + 4 * khalf) = v1;
    };

    // ---- prologue: tile 0 staged into buf0; tile 1 in regs ----
    loadt(0);
    stage(0);
    loadt(1);

    #pragma unroll 1
    for (int j = 0; j < jmax; ++j) {
        BAR_LGKM();   // buf[j&1] visible to all waves; buf[(j+1)&1] free
        const int cur = j & 1;
        const int T   = tB + j;

        if (T <= span) {
            __builtin_amdgcn_s_setprio(1);
            // ---- S^T = K Q^T : one 32x32 frag over 4 d-chunks ----
            f32x16 sT = {};
            #pragma unroll
            for (int cc = 0; cc < 4; ++cc) {
                bf16x8 kf = *(const bf16x8*)KBp(kh, cur, n, (2 * cc + p) ^ (n & 7));
                sT = __builtin_amdgcn_mfma_f32_32x32x16_bf16(kf, qf[cc], sT, 0, 0, 0);
            }

            const bool diag = (T == span);
            float ts = 0.f;
            #pragma unroll
            for (int r = 0; r < 16; ++r) {
                float pe = __builtin_amdgcn_exp2f(sT[r]);   // scale folded into Q
                if (diag) {
                    const int kk = (r & 3) + 8 * (r >> 2) + 4 * p;
                    pe = (kk <= n) ? pe : 0.f;
                }
                sT[r] = pe;
                ts += pe;
            }
            l_own += ts;

            // ---- P: C-layout -> B-layout in-register ----
            unsigned a0 = pk2(sT[0],  sT[1]),  a1 = pk2(sT[2],  sT[3]);
            unsigned a2 = pk2(sT[4],  sT[5]),  a3 = pk2(sT[6],  sT[7]);
            unsigned b0 = pk2(sT[8],  sT[9]),  b1 = pk2(sT[10], sT[11]);
            unsigned b2 = pk2(sT[12], sT[13]), b3 = pk2(sT[14], sT[15]);
            plswap(a0, a2);
            plswap(a1, a3);
            plswap(b0, b2);
            plswap(b1, b3);
            PU pu0, pu1;
            pu0.u[0] = a0; pu0.u[1] = a1; pu0.u[2] = a2; pu0.u[3] = a3;
            pu1.u[0] = b0; pu1.u[1] = b1; pu1.u[2] = b2; pu1.u[3] = b3;
            bf16x8 pf0 = pu0.v;
            bf16x8 pf1 = pu1.v;

            // ---- O^T += V^T P^T ----
            const int swn = (n >> 1) & 3;
            #pragma unroll
            for (int dg = 0; dg < 2; ++dg) {
                bf16x8 vf0 = *(const bf16x8*)VTp(kh, cur, 32 * dg + n, p ^ swn);
                bf16x8 vf1 = *(const bf16x8*)VTp(kh, cur, 32 * dg + n, (2 + p) ^ swn);
                oT[dg] = __builtin_amdgcn_mfma_f32_32x32x16_bf16(vf0, pf0, oT[dg], 0, 0, 0);
                oT[dg] = __builtin_amdgcn_mfma_f32_32x32x16_bf16(vf1, pf1, oT[dg], 0, 0, 0);
            }
            __builtin_amdgcn_s_setprio(0);
        }

        // ---- stage tile j+1 into the other buffer; prefetch tile j+2 ----
        if (j + 1 < jmax) stage(cur ^ 1);
        if (j + 2 < jmax) loadt(j + 2);
    }

    // ---- combine key-halves per strip (partials additive: fixed-shift) ----
    float l_part = l_own + __shfl_xor(l_own, 32, 64);

    __syncthreads();                        // tile buffers dead; reuse as f32
    float* Os = (float*)smem;
    const int cb = w3 * 2112;               // 2048 O-partials + 64 l-partials

    if (kh == 1) {
        #pragma unroll
        for (int dg = 0; dg < 2; ++dg)
            #pragma unroll
            for (int r = 0; r < 16; ++r)
                Os[cb + (dg * 16 + r) * 64 + lane] = oT[dg][r];
        Os[cb + 2048 + lane] = l_part;
    }
    __syncthreads();
    if (kh == 0) {
        const float linv = 1.0f / (l_part + Os[cb + 2048 + lane]);
        #pragma unroll
        for (int dg = 0; dg < 2; ++dg) {
            #pragma unroll
            for (int u4 = 0; u4 < 4; ++u4) {
                f32x4 o;
                #pragma unroll
                for (int j = 0; j < 4; ++j) {
                    const int r = 4 * u4 + j;
                    o[j] = (oT[dg][r] + Os[cb + (dg * 16 + r) * 64 + lane]) * linv;
                }
                *(f32x4*)&Oh[(size_t)(R0 + n) * HD + dg * 32 + u4 * 8 + 4 * p] = o;
            }
        }
    }
}

extern "C" void kernel_launch(void* const* d_in, const int* in_sizes, int n_in,
                              void* d_out, int out_size, void* d_ws, size_t ws_size,
                              hipStream_t stream) {
    const float* Q = (const float*)d_in[0];
    const float* K = (const float*)d_in[1];
    const float* V = (const float*)d_in[2];
    // d_in[3]: causal mask — analytically tril, not read.
    float* O = (float*)d_out;

    dim3 grid(512);
    dim3 block(512);
    attn_fwd<<<grid, block, 0, stream>>>(Q, K, V, O);
}